// Round 3
// baseline (1026.610 us; speedup 1.0000x reference)
//
#include <hip/hip_runtime.h>

#define NN 100000
#define NE 1000000

// d_out layout in FLOAT32 elements, concatenated reference-return order
#define OUT_EA  6400000ull    // edge_attr echo
#define OUT_U   70400000ull   // u echo
#define OUT_EI  70401024ull   // edge_index echo (ints as floats)

typedef __attribute__((ext_vector_type(4))) int sv4;   // 4 SGPRs (A chunk, bitcast float)
typedef __attribute__((ext_vector_type(8))) int si8;   // 8 SGPRs (edge indices)

// Scalar loads: A-operand addresses are wave-uniform -> SMEM pipe, zero VALU.
#define SLOAD4(dst, base, imm) \
    asm volatile("s_load_dwordx4 %0, %1, %2" : "=s"(dst) : "s"(base), "i"(imm))
#define SLOAD8(dst, base, imm) \
    asm volatile("s_load_dwordx8 %0, %1, %2" : "=s"(dst) : "s"(base), "i"(imm))
// SMEM may return out-of-order: only lgkmcnt(0) is safe. sched_barrier keeps
// dependent fmacs from being hoisted above the wait (guide rule #18).
#define LGKM0() do { asm volatile("s_waitcnt lgkmcnt(0)" ::: "memory"); \
                     __builtin_amdgcn_sched_barrier(0); } while (0)

#define DECL_AB sv4 ca0,ca1,ca2,ca3,ca4,ca5,ca6,ca7, cb0,cb1,cb2,cb3,cb4,cb5,cb6,cb7

// Issue one 4-k chunk for all 8 rows: row m at byte offset m*256 + chunk*16.
#define ISSUE8(B, base, off) do { \
    SLOAD4(B##0, base, (off) + 0*256); SLOAD4(B##1, base, (off) + 1*256); \
    SLOAD4(B##2, base, (off) + 2*256); SLOAD4(B##3, base, (off) + 3*256); \
    SLOAD4(B##4, base, (off) + 4*256); SLOAD4(B##5, base, (off) + 5*256); \
    SLOAD4(B##6, base, (off) + 6*256); SLOAD4(B##7, base, (off) + 7*256); } while (0)

// 1 instruction per MAC: v_fmac acc, sgpr(A), vgpr(W)
#define FMAROW(m, B, k) \
    acc[m] = fmaf(__int_as_float(B[0]), wreg[(k)+0], acc[m]); \
    acc[m] = fmaf(__int_as_float(B[1]), wreg[(k)+1], acc[m]); \
    acc[m] = fmaf(__int_as_float(B[2]), wreg[(k)+2], acc[m]); \
    acc[m] = fmaf(__int_as_float(B[3]), wreg[(k)+3], acc[m]);

#define FMACHUNK(B, k) \
    FMAROW(0, B##0, k) FMAROW(1, B##1, k) FMAROW(2, B##2, k) FMAROW(3, B##3, k) \
    FMAROW(4, B##4, k) FMAROW(5, B##5, k) FMAROW(6, B##6, k) FMAROW(7, B##7, k)

// Precondition: ISSUE8(ca, base, 0); LGKM0(); already done (chunk 0 landed).
// Double-buffered: wait chunk c, issue chunk c+1 into the other buffer, fma chunk c.
#define GEMM16(base) \
             ISSUE8(cb, base, 16);  FMACHUNK(ca, 0)  \
    LGKM0(); ISSUE8(ca, base, 32);  FMACHUNK(cb, 4)  \
    LGKM0(); ISSUE8(cb, base, 48);  FMACHUNK(ca, 8)  \
    LGKM0(); ISSUE8(ca, base, 64);  FMACHUNK(cb, 12) \
    LGKM0(); ISSUE8(cb, base, 80);  FMACHUNK(ca, 16) \
    LGKM0(); ISSUE8(ca, base, 96);  FMACHUNK(cb, 20) \
    LGKM0(); ISSUE8(cb, base, 112); FMACHUNK(ca, 24) \
    LGKM0(); ISSUE8(ca, base, 128); FMACHUNK(cb, 28) \
    LGKM0(); ISSUE8(cb, base, 144); FMACHUNK(ca, 32) \
    LGKM0(); ISSUE8(ca, base, 160); FMACHUNK(cb, 36) \
    LGKM0(); ISSUE8(cb, base, 176); FMACHUNK(ca, 40) \
    LGKM0(); ISSUE8(ca, base, 192); FMACHUNK(cb, 44) \
    LGKM0(); ISSUE8(cb, base, 208); FMACHUNK(ca, 48) \
    LGKM0(); ISSUE8(ca, base, 224); FMACHUNK(cb, 52) \
    LGKM0(); ISSUE8(cb, base, 240); FMACHUNK(ca, 56) \
    LGKM0();                        FMACHUNK(cb, 60)

// Per-lane W row -> 64 VGPRs (one-time per wave; L2-cached 16KB read).
__device__ __forceinline__ void load_wrow(const float* __restrict__ W, int lane, float* wreg) {
    const float4* wr = (const float4*)(W + lane * 64);
#pragma unroll
    for (int c = 0; c < 16; c++) {
        float4 w4 = wr[c];
        wreg[c*4+0] = w4.x; wreg[c*4+1] = w4.y; wreg[c*4+2] = w4.z; wreg[c*4+3] = w4.w;
    }
}

// ---------------------------------------------------------------------------
// proj: blockIdx.y in {0,1,2}: o = x@W^T + b for {k,q,v}; y==3 zeroes agg.
// 16 rows per wave (2 groups of 8), no LDS, no barriers.
// ---------------------------------------------------------------------------
__global__ __launch_bounds__(256, 3) void proj_kernel(
    const float* __restrict__ x,
    const float* __restrict__ Wk, const float* __restrict__ bk,
    const float* __restrict__ Wq, const float* __restrict__ bq,
    const float* __restrict__ Wv, const float* __restrict__ bv,
    float* __restrict__ ko, float* __restrict__ qo, float* __restrict__ vo,
    float* __restrict__ agg)
{
    const int tid = threadIdx.x;

    if (blockIdx.y == 3) {               // zero agg: 6.4M floats = 1.6M float4
        const float4 z = make_float4(0.f, 0.f, 0.f, 0.f);
        for (int i = blockIdx.x * 256 + tid; i < 1600000; i += 400128)
            ((float4*)agg)[i] = z;
        return;
    }

    const int lane = tid & 63, wave = tid >> 6;
    const float* W = blockIdx.y == 0 ? Wk : blockIdx.y == 1 ? Wq : Wv;
    const float* b = blockIdx.y == 0 ? bk : blockIdx.y == 1 ? bq : bv;
    float*       o = blockIdx.y == 0 ? ko : blockIdx.y == 1 ? qo : vo;

    const int rbase = __builtin_amdgcn_readfirstlane(blockIdx.x * 64 + wave * 16);
    if (rbase >= NN) return;             // only last block's waves 2,3

    float wreg[64];
    load_wrow(W, lane, wreg);
    const float bias = b[lane];

    DECL_AB;
#pragma unroll
    for (int g = 0; g < 2; g++) {
        const float* abase = x + (size_t)(rbase + g * 8) * 64;
        ISSUE8(ca, abase, 0);
        LGKM0();
        float acc[8];
#pragma unroll
        for (int m = 0; m < 8; m++) acc[m] = bias;
        GEMM16(abase);
#pragma unroll
        for (int m = 0; m < 8; m++)
            o[(size_t)(rbase + g * 8 + m) * 64 + lane] = acc[m];
    }
}

// ---------------------------------------------------------------------------
// edge: per 8-edge group: s_load indices + chunk0 (one shared wait), issue
// gathers + echo loads, then SMEM-fed register GEMM (1 inst/MAC), then
// gated message + fire-and-forget atomic scatter.
// ---------------------------------------------------------------------------
__global__ __launch_bounds__(256, 3) void edge_kernel(
    const float* __restrict__ ea, const int* __restrict__ ei,
    const float* __restrict__ We, const float* __restrict__ be,
    const float* __restrict__ ko, const float* __restrict__ qo, const float* __restrict__ vo,
    float* __restrict__ agg, float* __restrict__ out)
{
    const int tid = threadIdx.x;
    const int lane = tid & 63, wave = tid >> 6;

    float wreg[64];
    load_wrow(We, lane, wreg);
    const float bias = be[lane];
    float* echo = out + OUT_EA;
    const int stride = gridDim.x * 32;

    DECL_AB;
    for (int gb = __builtin_amdgcn_readfirstlane(blockIdx.x * 32 + wave * 8);
         gb < NE; gb += stride) {
        const float* abase = ea + (size_t)gb * 64;

        // indices + chunk 0 share one lgkmcnt(0)
        si8 si_, ti_;
        SLOAD8(si_, ei + gb, 0);
        SLOAD8(ti_, ei + NE + gb, 0);
        ISSUE8(ca, abase, 0);
        LGKM0();

        // echo loads (consumed after GEMM) + k/q/v gathers (consumed in epilogue)
        const float4* vsrc = (const float4*)abase;
        float4 A0 = vsrc[lane];
        float4 A1 = vsrc[64 + lane];

        float kd[8], qj[8], vj[8];
#pragma unroll
        for (int m = 0; m < 8; m++) {
            int s = si_[m], t = ti_[m];
            kd[m] = ko[(size_t)t * 64 + lane];
            qj[m] = qo[(size_t)s * 64 + lane];
            vj[m] = vo[(size_t)s * 64 + lane];
        }

        float acc[8];
#pragma unroll
        for (int m = 0; m < 8; m++) acc[m] = bias;
        GEMM16(abase);

        // echo from registers (loads landed long ago)
        float4* ech = (float4*)(echo + (size_t)gb * 64);
        ech[lane] = A0;
        ech[64 + lane] = A1;

        // gated message + scatter
#pragma unroll
        for (int m = 0; m < 8; m++) {
            float ev = acc[m];
            float z = kd[m] + qj[m] + ev + ev;          // (k_i+e) + (q_j+e)
            float g = 1.0f / (1.0f + __expf(-z));
            atomicAdd(&agg[(size_t)ti_[m] * 64 + lane], g * (vj[m] + ev));
        }
    }
}

// ---------------------------------------------------------------------------
// final: out = relu(agg + x@Ws^T + bs); also echoes u and edge_index.
// ---------------------------------------------------------------------------
__global__ __launch_bounds__(256, 3) void final_kernel(
    const float* __restrict__ x, const float* __restrict__ Ws, const float* __restrict__ bs,
    const float* __restrict__ agg, const float* __restrict__ u,
    const int* __restrict__ ei, float* __restrict__ out)
{
    const int tid = threadIdx.x;
    const int lane = tid & 63, wave = tid >> 6;

    // echo u (1024) + edge_index (2M ints -> floats); 1563*256 = 400128 threads
    {
        int gtid = blockIdx.x * 256 + tid;
        if (gtid < 1024) out[OUT_U + gtid] = u[gtid];
        for (int i = gtid; i < 2000000; i += 400128)
            out[OUT_EI + i] = (float)ei[i];
    }

    const int rbase = __builtin_amdgcn_readfirstlane(blockIdx.x * 64 + wave * 16);
    if (rbase >= NN) return;

    float wreg[64];
    load_wrow(Ws, lane, wreg);
    const float bias = bs[lane];

    DECL_AB;
#pragma unroll
    for (int g = 0; g < 2; g++) {
        const int r0 = rbase + g * 8;
        const float* abase = x + (size_t)r0 * 64;
        ISSUE8(ca, abase, 0);
        LGKM0();
        float acc[8];
#pragma unroll
        for (int m = 0; m < 8; m++) acc[m] = bias;
        GEMM16(abase);
#pragma unroll
        for (int m = 0; m < 8; m++) {
            float r = acc[m] + agg[(size_t)(r0 + m) * 64 + lane];
            out[(size_t)(r0 + m) * 64 + lane] = r > 0.0f ? r : 0.0f;
        }
    }
}

extern "C" void kernel_launch(void* const* d_in, const int* in_sizes, int n_in,
                              void* d_out, int out_size, void* d_ws, size_t ws_size,
                              hipStream_t stream)
{
    const float* x  = (const float*)d_in[0];
    const int*   ei = (const int*)d_in[1];
    const float* ea = (const float*)d_in[2];
    const float* u  = (const float*)d_in[3];
    // d_in[4] = batch (unused by reference output)
    const float* Wk = (const float*)d_in[5];
    const float* bk = (const float*)d_in[6];
    const float* Wq = (const float*)d_in[7];
    const float* bq = (const float*)d_in[8];
    const float* Wv = (const float*)d_in[9];
    const float* bv = (const float*)d_in[10];
    const float* We = (const float*)d_in[11];
    const float* be = (const float*)d_in[12];
    const float* Ws = (const float*)d_in[13];
    const float* bs = (const float*)d_in[14];
    float* out = (float*)d_out;

    float* ws  = (float*)d_ws;
    float* ko  = ws;
    float* qo  = ws + 6400000;
    float* vo  = ws + 12800000;
    float* agg = ws + 19200000;

    proj_kernel <<<dim3(1563, 4), 256, 0, stream>>>(x, Wk, bk, Wq, bq, Wv, bv, ko, qo, vo, agg);
    edge_kernel <<<2048, 256, 0, stream>>>(ea, ei, We, be, ko, qo, vo, agg, out);
    final_kernel<<<1563, 256, 0, stream>>>(x, Ws, bs, agg, u, ei, out);
}

// Round 4
// 700.622 us; speedup vs baseline: 1.4653x; 1.4653x over previous
//
#include <hip/hip_runtime.h>

#define NN 100000
#define NE 1000000

// d_out layout in FLOAT32 elements, concatenated reference-return order
#define OUT_EA  6400000ull    // edge_attr echo
#define OUT_U   70400000ull   // u echo
#define OUT_EI  70401024ull   // edge_index echo (ints as floats)

typedef short bf16x8 __attribute__((ext_vector_type(8)));   // 8 bf16 (4 VGPRs)
typedef float f32x16 __attribute__((ext_vector_type(16)));  // MFMA 32x32 accumulator

#define Z16 {0.f,0.f,0.f,0.f,0.f,0.f,0.f,0.f,0.f,0.f,0.f,0.f,0.f,0.f,0.f,0.f}

#define MFMA(a, b, c) __builtin_amdgcn_mfma_f32_32x32x16_bf16((a), (b), (c), 0, 0, 0)

// fp32 -> bf16 round-to-nearest-even (bit trick; inputs are normal floats)
__device__ __forceinline__ short f2bf(float f) {
    unsigned u = __float_as_uint(f);
    u += 0x7fff + ((u >> 16) & 1);
    return (short)(u >> 16);
}
__device__ __forceinline__ bf16x8 pack8(float4 a, float4 b) {
    bf16x8 r;
    r[0] = f2bf(a.x); r[1] = f2bf(a.y); r[2] = f2bf(a.z); r[3] = f2bf(a.w);
    r[4] = f2bf(b.x); r[5] = f2bf(b.y); r[6] = f2bf(b.z); r[7] = f2bf(b.w);
    return r;
}

// B-frags from W[64][64] row-major (out n, in k); B[k][j=n] = W[n][k].
// frag[c][h]: lane l supplies B[k = c*16 + (l>>5)*8 + b][n = h*32 + (l&31)]
// -> 8 consecutive fp32 from W row (h*32 + ln) at k-offset c*16 + (l>>5)*8.
__device__ __forceinline__ void load_bfrags(const float* __restrict__ W, int lane,
                                            bf16x8 bf[4][2]) {
    const float4* w4 = (const float4*)W;
    const int ln = lane & 31, kh = lane >> 5;
#pragma unroll
    for (int c = 0; c < 4; c++)
#pragma unroll
        for (int h = 0; h < 2; h++) {
            const float4* p = w4 + (h * 32 + ln) * 16 + c * 4 + kh * 2;
            bf[c][h] = pack8(p[0], p[1]);
        }
}

// ---------------------------------------------------------------------------
// proj: blockIdx.y in {0,1,2}: o = x@W^T + b for {k,q,v}; y==3 zeroes agg.
// One MFMA 32-row tile per wave: 8 mfma + 8 float4 loads + 32 dword stores.
// D layout: col = lane&31 (+32 for acc1), row = (reg&3)+8*(reg>>2)+4*(lane>>5).
// ---------------------------------------------------------------------------
__global__ __launch_bounds__(256, 4) void proj_kernel(
    const float* __restrict__ x,
    const float* __restrict__ Wk, const float* __restrict__ bk,
    const float* __restrict__ Wq, const float* __restrict__ bq,
    const float* __restrict__ Wv, const float* __restrict__ bv,
    float* __restrict__ ko, float* __restrict__ qo, float* __restrict__ vo,
    float* __restrict__ agg)
{
    const int tid = threadIdx.x;

    if (blockIdx.y == 3) {               // zero agg: 6.4M floats = 1.6M float4
        const float4 z = make_float4(0.f, 0.f, 0.f, 0.f);
        for (int i = blockIdx.x * 256 + tid; i < 1600000; i += 200192)
            ((float4*)agg)[i] = z;
        return;
    }

    const int lane = tid & 63, wave = tid >> 6;
    const int ln = lane & 31, kh = lane >> 5;

    const int rbase = blockIdx.x * 128 + wave * 32;   // 782*128 = 100096
    if (rbase >= NN) return;             // only block 781 waves 1..3 (NN%128==32)

    const float* W = blockIdx.y == 0 ? Wk : blockIdx.y == 1 ? Wq : Wv;
    const float* b = blockIdx.y == 0 ? bk : blockIdx.y == 1 ? bq : bv;
    float*       o = blockIdx.y == 0 ? ko : blockIdx.y == 1 ? qo : vo;

    bf16x8 bf[4][2];
    load_bfrags(W, lane, bf);
    const float bias0 = b[ln], bias1 = b[32 + ln];

    f32x16 acc0 = Z16, acc1 = Z16;
    const float4* a4 = (const float4*)x + (size_t)(rbase + ln) * 16 + kh * 2;
#pragma unroll
    for (int c = 0; c < 4; c++) {
        bf16x8 af = pack8(a4[c * 4], a4[c * 4 + 1]);
        acc0 = MFMA(af, bf[c][0], acc0);
        acc1 = MFMA(af, bf[c][1], acc1);
    }

#pragma unroll
    for (int r = 0; r < 16; r++) {
        int row = rbase + (r & 3) + 8 * (r >> 2) + 4 * kh;
        o[(size_t)row * 64 + ln]      = acc0[r] + bias0;
        o[(size_t)row * 64 + 32 + ln] = acc1[r] + bias1;
    }
}

// ---------------------------------------------------------------------------
// edge: 32 edges per wave per group. e = ea@We^T + be via MFMA (bf16 in,
// fp32 acc); echo written from the same fp32 registers feeding the convert.
// Edge indices via wave-private LDS table (64 ints); epilogue per D-reg:
// gather k/q/v (2x128B coalesced segments per load inst), gate, atomic.
// ---------------------------------------------------------------------------
__global__ __launch_bounds__(256, 3) void edge_kernel(
    const float* __restrict__ ea, const int* __restrict__ ei,
    const float* __restrict__ We, const float* __restrict__ be,
    const float* __restrict__ ko, const float* __restrict__ qo, const float* __restrict__ vo,
    float* __restrict__ agg, float* __restrict__ out)
{
    __shared__ int idx_lds[4][2][32];    // [wave][s/t][edge-in-group]
    const int tid = threadIdx.x;
    const int lane = tid & 63, wave = tid >> 6;
    const int ln = lane & 31, kh = lane >> 5;

    bf16x8 bf[4][2];
    load_bfrags(We, lane, bf);
    const float be0 = be[ln], be1 = be[32 + ln];
    float* echo = out + OUT_EA;

    for (int gb = blockIdx.x * 128 + wave * 32; gb < NE; gb += gridDim.x * 128) {
        // one index load per lane: kh==0 -> src, kh==1 -> dst (wave-private LDS)
        idx_lds[wave][kh][ln] = ei[kh * NE + gb + ln];

        // A rows: lane covers row gb+ln, k-offset (l>>5)*8, 4 chunks of 16 k
        const float4* a4 = (const float4*)ea + (size_t)(gb + ln) * 16 + kh * 2;
        float4*       e4 = (float4*)echo    + (size_t)(gb + ln) * 16 + kh * 2;

        f32x16 acc0 = Z16, acc1 = Z16;
#pragma unroll
        for (int c = 0; c < 4; c++) {
            float4 f0 = a4[c * 4], f1 = a4[c * 4 + 1];
            e4[c * 4] = f0; e4[c * 4 + 1] = f1;          // identity echo
            bf16x8 af = pack8(f0, f1);
            acc0 = MFMA(af, bf[c][0], acc0);
            acc1 = MFMA(af, bf[c][1], acc1);
        }

        // epilogue: per D-reg, row = (r&3)+8*(r>>2)+4*kh (edge gb+row)
#pragma unroll
        for (int r = 0; r < 16; r++) {
            int row = (r & 3) + 8 * (r >> 2) + 4 * kh;
            int s = idx_lds[wave][0][row];
            int t = idx_lds[wave][1][row];
            int tb = t * 64, sb = s * 64;
            float ev0 = acc0[r] + be0, ev1 = acc1[r] + be1;
            float kd0 = ko[tb + ln],      kd1 = ko[tb + 32 + ln];
            float qj0 = qo[sb + ln],      qj1 = qo[sb + 32 + ln];
            float vj0 = vo[sb + ln],      vj1 = vo[sb + 32 + ln];
            float z0 = kd0 + qj0 + ev0 + ev0;            // (k_i+e) + (q_j+e)
            float z1 = kd1 + qj1 + ev1 + ev1;
            float g0 = 1.0f / (1.0f + __expf(-z0));
            float g1 = 1.0f / (1.0f + __expf(-z1));
            atomicAdd(&agg[tb + ln],      g0 * (vj0 + ev0));
            atomicAdd(&agg[tb + 32 + ln], g1 * (vj1 + ev1));
        }
    }
}

// ---------------------------------------------------------------------------
// final: out = relu(agg + x@Ws^T + bs) via MFMA; also echoes u and edge_index.
// ---------------------------------------------------------------------------
__global__ __launch_bounds__(256, 4) void final_kernel(
    const float* __restrict__ x, const float* __restrict__ Ws, const float* __restrict__ bs,
    const float* __restrict__ agg, const float* __restrict__ u,
    const int* __restrict__ ei, float* __restrict__ out)
{
    const int tid = threadIdx.x;
    const int lane = tid & 63, wave = tid >> 6;
    const int ln = lane & 31, kh = lane >> 5;

    // echo u (1024) + edge_index (2M ints -> floats); 782*256 = 200192 threads
    {
        int gtid = blockIdx.x * 256 + tid;
        if (gtid < 1024) out[OUT_U + gtid] = u[gtid];
        for (int i = gtid; i < 2000000; i += 200192)
            out[OUT_EI + i] = (float)ei[i];
    }

    const int rbase = blockIdx.x * 128 + wave * 32;
    if (rbase >= NN) return;

    bf16x8 bf[4][2];
    load_bfrags(Ws, lane, bf);
    const float bias0 = bs[ln], bias1 = bs[32 + ln];

    f32x16 acc0 = Z16, acc1 = Z16;
    const float4* a4 = (const float4*)x + (size_t)(rbase + ln) * 16 + kh * 2;
#pragma unroll
    for (int c = 0; c < 4; c++) {
        bf16x8 af = pack8(a4[c * 4], a4[c * 4 + 1]);
        acc0 = MFMA(af, bf[c][0], acc0);
        acc1 = MFMA(af, bf[c][1], acc1);
    }

#pragma unroll
    for (int r = 0; r < 16; r++) {
        int row = rbase + (r & 3) + 8 * (r >> 2) + 4 * kh;
        float r0 = acc0[r] + bias0 + agg[(size_t)row * 64 + ln];
        float r1 = acc1[r] + bias1 + agg[(size_t)row * 64 + 32 + ln];
        out[(size_t)row * 64 + ln]      = r0 > 0.0f ? r0 : 0.0f;
        out[(size_t)row * 64 + 32 + ln] = r1 > 0.0f ? r1 : 0.0f;
    }
}

extern "C" void kernel_launch(void* const* d_in, const int* in_sizes, int n_in,
                              void* d_out, int out_size, void* d_ws, size_t ws_size,
                              hipStream_t stream)
{
    const float* x  = (const float*)d_in[0];
    const int*   ei = (const int*)d_in[1];
    const float* ea = (const float*)d_in[2];
    const float* u  = (const float*)d_in[3];
    // d_in[4] = batch (unused by reference output)
    const float* Wk = (const float*)d_in[5];
    const float* bk = (const float*)d_in[6];
    const float* Wq = (const float*)d_in[7];
    const float* bq = (const float*)d_in[8];
    const float* Wv = (const float*)d_in[9];
    const float* bv = (const float*)d_in[10];
    const float* We = (const float*)d_in[11];
    const float* be = (const float*)d_in[12];
    const float* Ws = (const float*)d_in[13];
    const float* bs = (const float*)d_in[14];
    float* out = (float*)d_out;

    float* ws  = (float*)d_ws;
    float* ko  = ws;
    float* qo  = ws + 6400000;
    float* vo  = ws + 12800000;
    float* agg = ws + 19200000;

    proj_kernel <<<dim3(782, 4), 256, 0, stream>>>(x, Wk, bk, Wq, bq, Wv, bv, ko, qo, vo, agg);
    edge_kernel <<<2048, 256, 0, stream>>>(ea, ei, We, be, ko, qo, vo, agg, out);
    final_kernel<<<782, 256, 0, stream>>>(x, Ws, bs, agg, u, ei, out);
}

// Round 5
// 660.095 us; speedup vs baseline: 1.5552x; 1.0614x over previous
//
#include <hip/hip_runtime.h>

#define NN 100000
#define NE 1000000

// d_out layout in FLOAT32 elements, concatenated reference-return order
#define OUT_EA  6400000ull    // edge_attr echo
#define OUT_U   70400000ull   // u echo
#define OUT_EI  70401024ull   // edge_index echo (ints as floats)

typedef short bf16x8 __attribute__((ext_vector_type(8)));   // 8 bf16 (4 VGPRs)
typedef float f32x16 __attribute__((ext_vector_type(16)));  // MFMA 32x32 accumulator

#define Z16 {0.f,0.f,0.f,0.f,0.f,0.f,0.f,0.f,0.f,0.f,0.f,0.f,0.f,0.f,0.f,0.f}

#define MFMA(a, b, c) __builtin_amdgcn_mfma_f32_32x32x16_bf16((a), (b), (c), 0, 0, 0)

// fp32 -> bf16 round-to-nearest-even (bit trick; inputs are normal floats)
__device__ __forceinline__ unsigned f2bf(float f) {
    unsigned u = __float_as_uint(f);
    u += 0x7fff + ((u >> 16) & 1);
    return u >> 16;
}
__device__ __forceinline__ float bf2f(unsigned lo16) {       // lo 16 bits = bf16
    return __uint_as_float(lo16 << 16);
}
__device__ __forceinline__ bf16x8 pack8(float4 a, float4 b) {
    bf16x8 r;
    r[0] = (short)f2bf(a.x); r[1] = (short)f2bf(a.y); r[2] = (short)f2bf(a.z); r[3] = (short)f2bf(a.w);
    r[4] = (short)f2bf(b.x); r[5] = (short)f2bf(b.y); r[6] = (short)f2bf(b.z); r[7] = (short)f2bf(b.w);
    return r;
}

// B-frags from W[64][64] row-major (out n, in k); B[k][j=n] = W[n][k].
// frag[c][h]: lane l supplies B[k = c*16 + (l>>5)*8 + b][n = h*32 + (l&31)]
__device__ __forceinline__ void load_bfrags(const float* __restrict__ W, int lane,
                                            bf16x8 bf[4][2]) {
    const float4* w4 = (const float4*)W;
    const int ln = lane & 31, kh = lane >> 5;
#pragma unroll
    for (int c = 0; c < 4; c++)
#pragma unroll
        for (int h = 0; h < 2; h++) {
            const float4* p = w4 + (h * 32 + ln) * 16 + c * 4 + kh * 2;
            bf[c][h] = pack8(p[0], p[1]);
        }
}

// ---------------------------------------------------------------------------
// proj (y==0): k,q,v in ONE pass (x read once, 24 MFMA/wave).
//   k  -> bf16  k16[node][64]
//   q,v-> packed qv[node][64] uint: lo16 = q (bf16), hi16 = v (bf16)
// proj (y==1): zero agg.
// D layout: col = ln (+32 for acc1), row = (r&3)+8*(r>>2)+4*kh.
// ---------------------------------------------------------------------------
__global__ __launch_bounds__(256, 2) void proj_kernel(
    const float* __restrict__ x,
    const float* __restrict__ Wk, const float* __restrict__ bk,
    const float* __restrict__ Wq, const float* __restrict__ bq,
    const float* __restrict__ Wv, const float* __restrict__ bv,
    unsigned short* __restrict__ k16, unsigned* __restrict__ qv,
    float* __restrict__ agg)
{
    const int tid = threadIdx.x;

    if (blockIdx.y == 1) {               // zero agg: 6.4M floats = 1.6M float4
        const float4 z = make_float4(0.f, 0.f, 0.f, 0.f);
        for (int i = blockIdx.x * 256 + tid; i < 1600000; i += 200192)
            ((float4*)agg)[i] = z;
        return;
    }

    const int lane = tid & 63, wave = tid >> 6;
    const int ln = lane & 31, kh = lane >> 5;

    const int rbase = blockIdx.x * 128 + wave * 32;   // 782*128 = 100096
    if (rbase >= NN) return;             // NN%32==0: tiles always full

    bf16x8 bk_[4][2], bq_[4][2], bv_[4][2];
    load_bfrags(Wk, lane, bk_);
    load_bfrags(Wq, lane, bq_);
    load_bfrags(Wv, lane, bv_);
    const float k0 = bk[ln], k1 = bk[32 + ln];
    const float q0 = bq[ln], q1 = bq[32 + ln];
    const float v0 = bv[ln], v1 = bv[32 + ln];

    f32x16 ak0 = Z16, ak1 = Z16, aq0 = Z16, aq1 = Z16, av0 = Z16, av1 = Z16;
    const float4* a4 = (const float4*)x + (size_t)(rbase + ln) * 16 + kh * 2;
#pragma unroll
    for (int c = 0; c < 4; c++) {
        bf16x8 af = pack8(a4[c * 4], a4[c * 4 + 1]);
        ak0 = MFMA(af, bk_[c][0], ak0); ak1 = MFMA(af, bk_[c][1], ak1);
        aq0 = MFMA(af, bq_[c][0], aq0); aq1 = MFMA(af, bq_[c][1], aq1);
        av0 = MFMA(af, bv_[c][0], av0); av1 = MFMA(af, bv_[c][1], av1);
    }

#pragma unroll
    for (int r = 0; r < 16; r++) {
        size_t row = rbase + (r & 3) + 8 * (r >> 2) + 4 * kh;
        k16[row * 64 + ln]      = (unsigned short)f2bf(ak0[r] + k0);
        k16[row * 64 + 32 + ln] = (unsigned short)f2bf(ak1[r] + k1);
        qv[row * 64 + ln]      = f2bf(aq0[r] + q0) | (f2bf(av0[r] + v0) << 16);
        qv[row * 64 + 32 + ln] = f2bf(aq1[r] + q1) | (f2bf(av1[r] + v1) << 16);
    }
}

// ---------------------------------------------------------------------------
// edge: MFMA front-end (e = ea@We^T + be, echo from the same registers),
// then BATCHED epilogue: 2 batches x 8 D-regs; each batch issues its 32
// gather loads (bf16 k, packed q|v) into arrays first -> one latency
// exposure per batch instead of 16 dependent chains.
// ---------------------------------------------------------------------------
__global__ __launch_bounds__(256, 3) void edge_kernel(
    const float* __restrict__ ea, const int* __restrict__ ei,
    const float* __restrict__ We, const float* __restrict__ be,
    const unsigned short* __restrict__ k16, const unsigned* __restrict__ qv,
    float* __restrict__ agg, float* __restrict__ out)
{
    __shared__ int idx_lds[4][2][32];    // [wave][s/t][edge-in-group]
    const int tid = threadIdx.x;
    const int lane = tid & 63, wave = tid >> 6;
    const int ln = lane & 31, kh = lane >> 5;

    bf16x8 bf[4][2];
    load_bfrags(We, lane, bf);
    const float be0 = be[ln], be1 = be[32 + ln];
    float* echo = out + OUT_EA;

    for (int gb = blockIdx.x * 128 + wave * 32; gb < NE; gb += gridDim.x * 128) {
        // one index load per lane: kh==0 -> src, kh==1 -> dst (wave-private LDS)
        idx_lds[wave][kh][ln] = ei[kh * NE + gb + ln];

        const float4* a4 = (const float4*)ea + (size_t)(gb + ln) * 16 + kh * 2;
        float4*       e4 = (float4*)echo    + (size_t)(gb + ln) * 16 + kh * 2;

        f32x16 acc0 = Z16, acc1 = Z16;
#pragma unroll
        for (int c = 0; c < 4; c++) {
            float4 f0 = a4[c * 4], f1 = a4[c * 4 + 1];
            e4[c * 4] = f0; e4[c * 4 + 1] = f1;          // identity echo
            bf16x8 af = pack8(f0, f1);
            acc0 = MFMA(af, bf[c][0], acc0);
            acc1 = MFMA(af, bf[c][1], acc1);
        }

        // epilogue: row = (r&3)+8*(r>>2)+4*kh; halves handle different edges
#pragma unroll
        for (int h = 0; h < 2; h++) {
            int tb[8];
            unsigned kr0[8], kr1[8], s0[8], s1[8];
#pragma unroll
            for (int i = 0; i < 8; i++) {               // issue 32 gathers
                int r = h * 8 + i;
                int row = (r & 3) + 8 * (r >> 2) + 4 * kh;
                int s = idx_lds[wave][0][row];
                int t = idx_lds[wave][1][row];
                tb[i] = t * 64;
                int sb = s * 64;
                kr0[i] = k16[tb[i] + ln];
                kr1[i] = k16[tb[i] + 32 + ln];
                s0[i] = qv[sb + ln];
                s1[i] = qv[sb + 32 + ln];
            }
#pragma unroll
            for (int i = 0; i < 8; i++) {               // consume
                int r = h * 8 + i;
                float ev0 = acc0[r] + be0, ev1 = acc1[r] + be1;
                float kd0 = bf2f(kr0[i]),        kd1 = bf2f(kr1[i]);
                float qj0 = bf2f(s0[i] & 0xffffu), vj0 = __uint_as_float(s0[i] & 0xffff0000u);
                float qj1 = bf2f(s1[i] & 0xffffu), vj1 = __uint_as_float(s1[i] & 0xffff0000u);
                float z0 = kd0 + qj0 + ev0 + ev0;       // (k_i+e) + (q_j+e)
                float z1 = kd1 + qj1 + ev1 + ev1;
                float g0 = 1.0f / (1.0f + __expf(-z0));
                float g1 = 1.0f / (1.0f + __expf(-z1));
                atomicAdd(&agg[tb[i] + ln],      g0 * (vj0 + ev0));
                atomicAdd(&agg[tb[i] + 32 + ln], g1 * (vj1 + ev1));
            }
        }
    }
}

// ---------------------------------------------------------------------------
// final: out = relu(agg + x@Ws^T + bs) via MFMA; also echoes u and edge_index.
// ---------------------------------------------------------------------------
__global__ __launch_bounds__(256, 4) void final_kernel(
    const float* __restrict__ x, const float* __restrict__ Ws, const float* __restrict__ bs,
    const float* __restrict__ agg, const float* __restrict__ u,
    const int* __restrict__ ei, float* __restrict__ out)
{
    const int tid = threadIdx.x;
    const int lane = tid & 63, wave = tid >> 6;
    const int ln = lane & 31, kh = lane >> 5;

    // echo u (1024) + edge_index (2M ints -> floats); 782*256 = 200192 threads
    {
        int gtid = blockIdx.x * 256 + tid;
        if (gtid < 1024) out[OUT_U + gtid] = u[gtid];
        for (int i = gtid; i < 2000000; i += 200192)
            out[OUT_EI + i] = (float)ei[i];
    }

    const int rbase = blockIdx.x * 128 + wave * 32;
    if (rbase >= NN) return;

    bf16x8 bf[4][2];
    load_bfrags(Ws, lane, bf);
    const float bias0 = bs[ln], bias1 = bs[32 + ln];

    f32x16 acc0 = Z16, acc1 = Z16;
    const float4* a4 = (const float4*)x + (size_t)(rbase + ln) * 16 + kh * 2;
#pragma unroll
    for (int c = 0; c < 4; c++) {
        bf16x8 af = pack8(a4[c * 4], a4[c * 4 + 1]);
        acc0 = MFMA(af, bf[c][0], acc0);
        acc1 = MFMA(af, bf[c][1], acc1);
    }

#pragma unroll
    for (int r = 0; r < 16; r++) {
        size_t row = rbase + (r & 3) + 8 * (r >> 2) + 4 * kh;
        float r0 = acc0[r] + bias0 + agg[row * 64 + ln];
        float r1 = acc1[r] + bias1 + agg[row * 64 + 32 + ln];
        out[row * 64 + ln]      = r0 > 0.0f ? r0 : 0.0f;
        out[row * 64 + 32 + ln] = r1 > 0.0f ? r1 : 0.0f;
    }
}

extern "C" void kernel_launch(void* const* d_in, const int* in_sizes, int n_in,
                              void* d_out, int out_size, void* d_ws, size_t ws_size,
                              hipStream_t stream)
{
    const float* x  = (const float*)d_in[0];
    const int*   ei = (const int*)d_in[1];
    const float* ea = (const float*)d_in[2];
    const float* u  = (const float*)d_in[3];
    // d_in[4] = batch (unused by reference output)
    const float* Wk = (const float*)d_in[5];
    const float* bk = (const float*)d_in[6];
    const float* Wq = (const float*)d_in[7];
    const float* bq = (const float*)d_in[8];
    const float* Wv = (const float*)d_in[9];
    const float* bv = (const float*)d_in[10];
    const float* We = (const float*)d_in[11];
    const float* be = (const float*)d_in[12];
    const float* Ws = (const float*)d_in[13];
    const float* bs = (const float*)d_in[14];
    float* out = (float*)d_out;

    float* ws = (float*)d_ws;
    unsigned short* k16 = (unsigned short*)ws;            // 6.4M u16 = 3.2M floats
    unsigned*       qvp = (unsigned*)(ws + 3200000);      // 6.4M u32 = 6.4M floats
    float*          agg = ws + 9600000;                   // 6.4M floats

    proj_kernel <<<dim3(782, 2), 256, 0, stream>>>(x, Wk, bk, Wq, bq, Wv, bv, k16, qvp, agg);
    edge_kernel <<<2048, 256, 0, stream>>>(ea, ei, We, be, k16, qvp, agg, out);
    final_kernel<<<782, 256, 0, stream>>>(x, Ws, bs, agg, u, ei, out);
}